// Round 7
// baseline (205.462 us; speedup 1.0000x reference)
//
#include <hip/hip_runtime.h>
#include <hip/hip_bf16.h>
#include <stdint.h>

typedef unsigned short u16;
typedef __attribute__((ext_vector_type(8))) short short8;
typedef __attribute__((ext_vector_type(4))) float f32x4;

#define BB 4
#define NN 8192
#define SS 2048
#define MTOT 32768
#define CSKIP 256
#define CLO 512
#define CIN 768
#define COUT 256

__device__ __forceinline__ u16 f2bf(float f) {
  unsigned u = __float_as_uint(f);
  u += 0x7fffu + ((u >> 16) & 1u);
  return (u16)(u >> 16);
}

__device__ __forceinline__ void gl_lds16(const void* g, void* l) {
  __builtin_amdgcn_global_load_lds(
      (const __attribute__((address_space(1))) void*)g,
      (__attribute__((address_space(3))) void*)l, 16, 0, 0);
}

// ---------------------------------------------------------------------------
// K1: blocks 0..127 = KNN (K=3): 256 queries/block, 16 waves = 4 query-groups
// x 4 candidate-partitions of 512. lane = query. Candidates wave-uniform ->
// scalar/broadcast loads. R7: long (512) partitions enable the wave-uniform
// skip `if (__any(d < b2))` — all-lanes-fail prob ~(1-3/t)^64 is high only
// for t >> 64, so 512-partitions skip the 9-op insert ~40% of iters while
// 128-partitions almost never could. 4-way merge (was 16). 2 blocks/CU =
// 32 waves/CU for s_load latency hiding.
// blocks 128..191 = weight conversion (W1aT/W1bT/W2T), independent of knn.
// ---------------------------------------------------------------------------
__global__ __launch_bounds__(1024) void knn_wconv_kernel(
    const float* __restrict__ xyz_hi, const float* __restrict__ xyz_lo,
    const float* __restrict__ W1, const float* __restrict__ W2,
    float* __restrict__ wq_g, int* __restrict__ iq_g,
    u16* __restrict__ W1aT, u16* __restrict__ W1bT, u16* __restrict__ W2T) {
  int blk = blockIdx.x;
  int tid = threadIdx.x;
  if (blk >= 128) {
    // ---- wconv: 262144 elems over 64 blocks x 1024 thr (4 iters) ----
    int base = (blk - 128) * 1024 + tid;
    for (int i = base; i < 262144; i += 65536) {
      if (i < 65536) {                       // W1aT: n=i>>8, k=i&255
        int n = i >> 8, k = i & 255;
        W1aT[i] = f2bf(W1[(size_t)k * COUT + n]);
      } else if (i < 196608) {               // W1bT: n=j>>9, k=j&511
        int j = i - 65536;
        int n = j >> 9, k = j & 511;
        W1bT[j] = f2bf(W1[(size_t)(256 + k) * COUT + n]);
      } else {                               // W2T
        int j = i - 196608;
        int n = j >> 8, k = j & 255;
        W2T[j] = f2bf(W2[(size_t)k * COUT + n]);
      }
    }
    return;
  }

  // ---- knn ----
  __shared__ float md[16][64][3];
  __shared__ int   mi[16][64][3];

  int b = blk >> 5;                          // 32 blocks per batch
  int wave = tid >> 6, lane = tid & 63;
  int qg = wave >> 2, part = wave & 3;
  int qm = blk * 256 + qg * 64 + lane;
  float qx = xyz_hi[(size_t)qm * 3 + 0];
  float qy = xyz_hi[(size_t)qm * 3 + 1];
  float qz = xyz_hi[(size_t)qm * 3 + 2];

  const float* xl = xyz_lo + (size_t)b * SS * 3;
  int j0 = __builtin_amdgcn_readfirstlane(part * 512);

  float b0 = 1e30f, b1 = 1e30f, b2 = 1e30f;
  int i0 = -1, i1 = -1, i2 = -1;
#pragma unroll 8
  for (int jj = 0; jj < 512; ++jj) {
    int j = j0 + jj;
    float px = xl[3 * j + 0];            // uniform -> scalar load / broadcast
    float py = xl[3 * j + 1];
    float pz = xl[3 * j + 2];
    float dx = px - qx, dy = py - qy, dz = pz - qz;
    float d = fmaf(dx, dx, fmaf(dy, dy, dz * dz));
    if (__any(d < b2)) {                 // wave-uniform skip of the insert
      bool c0 = d < b0, c1 = d < b1, c2 = d < b2;
      float nb0 = fminf(b0, d);
      float nb1 = __builtin_amdgcn_fmed3f(b0, b1, d);
      float nb2 = __builtin_amdgcn_fmed3f(b1, b2, d);
      int ni0 = c0 ? j : i0;
      int ni1 = c0 ? i0 : (c1 ? j : i1);
      int ni2 = c1 ? i1 : (c2 ? j : i2);
      b0 = nb0; b1 = nb1; b2 = nb2;
      i0 = ni0; i1 = ni1; i2 = ni2;
    }
  }
  md[wave][lane][0] = b0; mi[wave][lane][0] = i0;
  md[wave][lane][1] = b1; mi[wave][lane][1] = i1;
  md[wave][lane][2] = b2; mi[wave][lane][2] = i2;
  __syncthreads();

  if (tid < 256) {
    int q = tid;
    int qgm = q >> 6, ql = q & 63;
    float fb0 = 1e30f, fb1 = 1e30f, fb2 = 1e30f;
    int fi0 = -1, fi1 = -1, fi2 = -1;
    // parts are contiguous ascending ranges; merge with index tiebreak
    for (int p = 0; p < 4; ++p)
#pragma unroll
      for (int s = 0; s < 3; ++s) {
        float d = md[qgm * 4 + p][ql][s]; int ix = mi[qgm * 4 + p][ql][s];
        if (d < fb2 || (d == fb2 && ix < fi2)) {
          fb2 = d; fi2 = ix;
          if (fb2 < fb1 || (fb2 == fb1 && fi2 < fi1)) {
            float t = fb1; fb1 = fb2; fb2 = t; int ti = fi1; fi1 = fi2; fi2 = ti;
          }
          if (fb1 < fb0 || (fb1 == fb0 && fi1 < fi0)) {
            float t = fb0; fb0 = fb1; fb1 = t; int ti = fi0; fi0 = fi1; fi1 = ti;
          }
        }
      }
    int qm2 = blk * 256 + q;
    float d0 = sqrtf(fb0), d1 = sqrtf(fb1), d2 = sqrtf(fb2);
    float inv0 = 1.0f / (d0 + 1e-8f);
    float inv1 = 1.0f / (d1 + 1e-8f);
    float inv2 = 1.0f / (d2 + 1e-8f);
    float s = inv0 + inv1 + inv2;
    wq_g[(size_t)qm2 * 3 + 0] = inv0 / s;
    wq_g[(size_t)qm2 * 3 + 1] = inv1 / s;
    wq_g[(size_t)qm2 * 3 + 2] = inv2 / s;
    iq_g[(size_t)qm2 * 3 + 0] = fi0;
    iq_g[(size_t)qm2 * 3 + 1] = fi1;
    iq_g[(size_t)qm2 * 3 + 2] = fi2;
  }
}

// ---------------------------------------------------------------------------
// K2: ggemm — G = feat_lo @ W1b  (dense, M=8192, K=512, N=256, fp32 out).
// Tile 32x128 (N split in 2), 256 thr, BK=32, grid 512 -> 4 blocks/CU.
// Double-buffered As/Bs: stage kc+1 while computing kc; 1 barrier/kc.
// (R5-measured as part of the 178.5 total; unchanged.)
// ---------------------------------------------------------------------------
__global__ __launch_bounds__(256, 4) void ggemm_kernel(
    const float* __restrict__ feat_lo, const u16* __restrict__ W1bT,
    float* __restrict__ G) {
  __shared__ u16 As[2][32 * 40];
  __shared__ u16 Bs[2][128 * 32];
  int tid = threadIdx.x;
  int m0 = (blockIdx.x >> 1) << 5;
  int n0 = (blockIdx.x & 1) << 7;
  int w = tid >> 6, lane = tid & 63;
  int quad = lane >> 4, l16 = lane & 15;

  int srow = tid >> 3, s4 = (tid & 7) << 2;
  const float* arow = feat_lo + (size_t)(m0 + srow) * CLO + s4;

  f32x4 zero = {0.f, 0.f, 0.f, 0.f};
  f32x4 acc[2][2];
#pragma unroll
  for (int tm = 0; tm < 2; ++tm)
#pragma unroll
    for (int tn = 0; tn < 2; ++tn) acc[tm][tn] = zero;

  // prologue: stage kc=0 into buffer 0
#pragma unroll
  for (int r = 0; r < 2; ++r) {
    int u = tid + r * 256;
    int nrow = u >> 2, c = u & 3;
    int cg = c ^ (nrow & 3);
    gl_lds16(W1bT + (size_t)(n0 + nrow) * CLO + cg * 8, (char*)Bs[0] + u * 16);
  }
  {
    float4 av = *(const float4*)(arow);
    union { __hip_bfloat162 h2[2]; uint2 u2; } pk;
    pk.h2[0] = __float22bfloat162_rn(make_float2(av.x, av.y));
    pk.h2[1] = __float22bfloat162_rn(make_float2(av.z, av.w));
    *(uint2*)(As[0] + srow * 40 + s4) = pk.u2;
  }

  for (int kc = 0; kc < 16; ++kc) {
    __syncthreads();             // buf[cur] staged+visible; buf[nxt] reads done
    const u16* Ac = As[kc & 1];
    const u16* Bc = Bs[kc & 1];
    if (kc + 1 < 16) {
      u16* An = As[(kc + 1) & 1];
      u16* Bn = Bs[(kc + 1) & 1];
#pragma unroll
      for (int r = 0; r < 2; ++r) {
        int u = tid + r * 256;
        int nrow = u >> 2, c = u & 3;
        int cg = c ^ (nrow & 3);
        gl_lds16(W1bT + (size_t)(n0 + nrow) * CLO + (kc + 1) * 32 + cg * 8,
                 (char*)Bn + u * 16);
      }
      float4 av = *(const float4*)(arow + (kc + 1) * 32);
      union { __hip_bfloat162 h2[2]; uint2 u2; } pk;
      pk.h2[0] = __float22bfloat162_rn(make_float2(av.x, av.y));
      pk.h2[1] = __float22bfloat162_rn(make_float2(av.z, av.w));
      *(uint2*)(An + srow * 40 + s4) = pk.u2;
    }

    short8 af[2], bf[2];
#pragma unroll
    for (int t = 0; t < 2; ++t)
      af[t] = *(const short8*)(Ac + (t * 16 + l16) * 40 + quad * 8);
#pragma unroll
    for (int t = 0; t < 2; ++t) {
      int rr = w * 32 + t * 16 + l16;
      bf[t] = *(const short8*)(Bc + (rr * 4 + (quad ^ (rr & 3))) * 8);
    }
#pragma unroll
    for (int tm = 0; tm < 2; ++tm)
#pragma unroll
      for (int tn = 0; tn < 2; ++tn)
        acc[tm][tn] = __builtin_amdgcn_mfma_f32_16x16x32_bf16(af[tm], bf[tn], acc[tm][tn], 0, 0, 0);
  }

#pragma unroll
  for (int tm = 0; tm < 2; ++tm)
#pragma unroll
    for (int tn = 0; tn < 2; ++tn) {
      int col = n0 + w * 32 + tn * 16 + l16;
#pragma unroll
      for (int r = 0; r < 4; ++r) {
        int row = m0 + tm * 16 + quad * 4 + r;
        G[(size_t)row * COUT + col] = acc[tm][tn][r];
      }
    }
}

// ---------------------------------------------------------------------------
// K3: fused MLP — phase 1: Htile = relu(skip@W1a + b1 + IDW-gather(G)) -> LDS
// (bf16, rows padded to 264); phase 2: out = LN(Htile@W2 + b2).
// R5-measured (~37 µs): 64-row tile, serial-tail gather, both phases
// double-buffered, 1 barrier/kc. LDS 80896 -> 2 blocks/CU. Unchanged.
// ---------------------------------------------------------------------------
__global__ __launch_bounds__(256, 2) void gemm12_kernel(
    const float* __restrict__ feat_skip, const u16* __restrict__ W1aT,
    const float* __restrict__ b1, const float* __restrict__ G,
    const float* __restrict__ wq_g, const int* __restrict__ iq_g,
    const u16* __restrict__ W2T, const float* __restrict__ b2,
    const float* __restrict__ gamma, const float* __restrict__ beta,
    float* __restrict__ out) {
  __shared__ u16 Hs[64 * 264];
  __shared__ u16 Bs[256 * 32];
  __shared__ u16 Bs2[256 * 32];
  __shared__ u16 As[2][64 * 40];
  __shared__ float swq[192];
  __shared__ int   siq[192];
  __shared__ float red[4][64][2];
  __shared__ float stats[64][2];
  int tid = threadIdx.x;
  int m0 = blockIdx.x << 6;
  int bS = (m0 >> 13) * SS;
  int w = tid >> 6, lane = tid & 63;
  int quad = lane >> 4, l16 = lane & 15;

  if (tid < 192) {
    swq[tid] = wq_g[(size_t)m0 * 3 + tid];
    siq[tid] = iq_g[(size_t)m0 * 3 + tid];
  }

  int srow = tid >> 2, sc8 = (tid & 3) << 3;
  const float* arow = feat_skip + (size_t)(m0 + srow) * CSKIP + sc8;

  f32x4 zero = {0.f, 0.f, 0.f, 0.f};
  f32x4 acc[4][4];
#pragma unroll
  for (int tm = 0; tm < 4; ++tm)
#pragma unroll
    for (int tn = 0; tn < 4; ++tn) acc[tm][tn] = zero;

  // ---- phase 1 prologue: stage kc=0 (Bs <- W1aT, As[0] <- feat_skip) ----
#pragma unroll
  for (int r = 0; r < 4; ++r) {
    int u = tid + r * 256;
    int nrow = u >> 2, c = u & 3;
    int cg = c ^ (nrow & 3);
    gl_lds16(W1aT + (size_t)nrow * CSKIP + cg * 8, (char*)Bs + u * 16);
  }
  {
    float4 x0 = *(const float4*)(arow);
    float4 x1 = *(const float4*)(arow + 4);
    union { __hip_bfloat162 h2[4]; uint4 u4; } pk;
    pk.h2[0] = __float22bfloat162_rn(make_float2(x0.x, x0.y));
    pk.h2[1] = __float22bfloat162_rn(make_float2(x0.z, x0.w));
    pk.h2[2] = __float22bfloat162_rn(make_float2(x1.x, x1.y));
    pk.h2[3] = __float22bfloat162_rn(make_float2(x1.z, x1.w));
    *(uint4*)(As[0] + srow * 40 + sc8) = pk.u4;
  }

  // ---- phase 1: skip @ W1a — double-buffered, 1 barrier/kc ----
  for (int kc = 0; kc < 8; ++kc) {
    __syncthreads();             // buf[cur] staged+visible; buf[nxt] reads done
    const u16* Ac = As[kc & 1];
    u16* Bc = (kc & 1) ? Bs2 : Bs;
    if (kc + 1 < 8) {
      u16* An = As[(kc + 1) & 1];
      u16* Bn = (kc & 1) ? Bs : Bs2;
#pragma unroll
      for (int r = 0; r < 4; ++r) {
        int u = tid + r * 256;
        int nrow = u >> 2, c = u & 3;
        int cg = c ^ (nrow & 3);
        gl_lds16(W1aT + (size_t)nrow * CSKIP + (kc + 1) * 32 + cg * 8,
                 (char*)Bn + u * 16);
      }
      float4 x0 = *(const float4*)(arow + (kc + 1) * 32);
      float4 x1 = *(const float4*)(arow + (kc + 1) * 32 + 4);
      union { __hip_bfloat162 h2[4]; uint4 u4; } pk;
      pk.h2[0] = __float22bfloat162_rn(make_float2(x0.x, x0.y));
      pk.h2[1] = __float22bfloat162_rn(make_float2(x0.z, x0.w));
      pk.h2[2] = __float22bfloat162_rn(make_float2(x1.x, x1.y));
      pk.h2[3] = __float22bfloat162_rn(make_float2(x1.z, x1.w));
      *(uint4*)(An + srow * 40 + sc8) = pk.u4;
    }

    short8 af[4], bf[4];
#pragma unroll
    for (int t = 0; t < 4; ++t)
      af[t] = *(const short8*)(Ac + (t * 16 + l16) * 40 + quad * 8);
#pragma unroll
    for (int t = 0; t < 4; ++t) {
      int rr = w * 64 + t * 16 + l16;
      bf[t] = *(const short8*)(Bc + (rr * 4 + (quad ^ (rr & 3))) * 8);
    }
#pragma unroll
    for (int tm = 0; tm < 4; ++tm)
#pragma unroll
      for (int tn = 0; tn < 4; ++tn)
        acc[tm][tn] = __builtin_amdgcn_mfma_f32_16x16x32_bf16(af[tm], bf[tn], acc[tm][tn], 0, 0, 0);
  }

  // ---- phase 1 epilogue: bias + serial IDW gather + relu -> Hs ----
  {
    float bias[4];
#pragma unroll
    for (int tn = 0; tn < 4; ++tn) bias[tn] = b1[w * 64 + tn * 16 + l16];
#pragma unroll
    for (int tm = 0; tm < 4; ++tm)
#pragma unroll
      for (int r = 0; r < 4; ++r) {
        int rl = tm * 16 + quad * 4 + r;
        float w0 = swq[rl * 3 + 0], w1 = swq[rl * 3 + 1], w2 = swq[rl * 3 + 2];
        const float* g0 = G + (size_t)(bS + siq[rl * 3 + 0]) * COUT;
        const float* g1 = G + (size_t)(bS + siq[rl * 3 + 1]) * COUT;
        const float* g2 = G + (size_t)(bS + siq[rl * 3 + 2]) * COUT;
#pragma unroll
        for (int tn = 0; tn < 4; ++tn) {
          int col = w * 64 + tn * 16 + l16;
          float gv = fmaf(w0, g0[col], fmaf(w1, g1[col], w2 * g2[col]));
          float v = acc[tm][tn][r] + bias[tn] + gv;
          v = v > 0.f ? v : 0.f;
          Hs[rl * 264 + col] = f2bf(v);
        }
      }
  }

  // ---- phase 2: Hs @ W2 + LN, double-buffered B, 1 barrier/iter ----
#pragma unroll
  for (int tm = 0; tm < 4; ++tm)
#pragma unroll
    for (int tn = 0; tn < 4; ++tn) acc[tm][tn] = zero;

  __syncthreads();               // Hs writes visible; phase-1 Bs reads done
#pragma unroll
  for (int r = 0; r < 4; ++r) {  // stage kc=0 into Bs
    int u = tid + r * 256;
    int nrow = u >> 2, c = u & 3;
    int cg = c ^ (nrow & 3);
    gl_lds16(W2T + (size_t)nrow * COUT + cg * 8, (char*)Bs + u * 16);
  }
  for (int kc = 0; kc < 8; ++kc) {
    __syncthreads();             // B(kc) staged (vmcnt drained at barrier)
    u16* cur = (kc & 1) ? Bs2 : Bs;
    u16* nxt = (kc & 1) ? Bs : Bs2;
    if (kc + 1 < 8) {
#pragma unroll
      for (int r = 0; r < 4; ++r) {
        int u = tid + r * 256;
        int nrow = u >> 2, c = u & 3;
        int cg = c ^ (nrow & 3);
        gl_lds16(W2T + (size_t)nrow * COUT + (kc + 1) * 32 + cg * 8,
                 (char*)nxt + u * 16);
      }
    }
    short8 af[4], bf[4];
#pragma unroll
    for (int t = 0; t < 4; ++t)
      af[t] = *(const short8*)(Hs + (t * 16 + l16) * 264 + kc * 32 + quad * 8);
#pragma unroll
    for (int t = 0; t < 4; ++t) {
      int rr = w * 64 + t * 16 + l16;
      bf[t] = *(const short8*)(cur + (rr * 4 + (quad ^ (rr & 3))) * 8);
    }
#pragma unroll
    for (int tm = 0; tm < 4; ++tm)
#pragma unroll
      for (int tn = 0; tn < 4; ++tn)
        acc[tm][tn] = __builtin_amdgcn_mfma_f32_16x16x32_bf16(af[tm], bf[tn], acc[tm][tn], 0, 0, 0);
  }

  float bias[4], g[4], be[4];
#pragma unroll
  for (int tn = 0; tn < 4; ++tn) {
    int col = w * 64 + tn * 16 + l16;
    bias[tn] = b2[col]; g[tn] = gamma[col]; be[tn] = beta[col];
  }
#pragma unroll
  for (int tm = 0; tm < 4; ++tm)
#pragma unroll
    for (int r = 0; r < 4; ++r) {
      float s = 0.f, sq = 0.f;
#pragma unroll
      for (int tn = 0; tn < 4; ++tn) {
        float v = acc[tm][tn][r] + bias[tn];
        acc[tm][tn][r] = v;
        s += v; sq += v * v;
      }
#pragma unroll
      for (int msk = 1; msk < 16; msk <<= 1) {
        s += __shfl_xor(s, msk);
        sq += __shfl_xor(sq, msk);
      }
      if (l16 == 0) {
        int rl = tm * 16 + quad * 4 + r;
        red[w][rl][0] = s;
        red[w][rl][1] = sq;
      }
    }
  __syncthreads();
  if (tid < 64) {
    float s = red[0][tid][0] + red[1][tid][0] + red[2][tid][0] + red[3][tid][0];
    float sq = red[0][tid][1] + red[1][tid][1] + red[2][tid][1] + red[3][tid][1];
    float mu = s * (1.f / 256.f);
    float var = sq * (1.f / 256.f) - mu * mu;
    stats[tid][0] = mu;
    stats[tid][1] = rsqrtf(var + 1e-5f);
  }
  __syncthreads();
#pragma unroll
  for (int tm = 0; tm < 4; ++tm)
#pragma unroll
    for (int r = 0; r < 4; ++r) {
      int rl = tm * 16 + quad * 4 + r;
      float mu = stats[rl][0], rstd = stats[rl][1];
#pragma unroll
      for (int tn = 0; tn < 4; ++tn) {
        int col = w * 64 + tn * 16 + l16;
        out[(size_t)(m0 + rl) * COUT + col] = (acc[tm][tn][r] - mu) * rstd * g[tn] + be[tn];
      }
    }
}

// ---------------------------------------------------------------------------
extern "C" void kernel_launch(void* const* d_in, const int* in_sizes, int n_in,
                              void* d_out, int out_size, void* d_ws, size_t ws_size,
                              hipStream_t stream) {
  const float* xyz_hi    = (const float*)d_in[0];
  const float* xyz_lo    = (const float*)d_in[1];
  const float* feat_skip = (const float*)d_in[2];
  const float* feat_lo   = (const float*)d_in[3];
  const float* W1        = (const float*)d_in[4];
  const float* b1        = (const float*)d_in[5];
  const float* W2        = (const float*)d_in[6];
  const float* b2        = (const float*)d_in[7];
  const float* gamma     = (const float*)d_in[8];
  const float* beta      = (const float*)d_in[9];
  float* out = (float*)d_out;

  char* ws = (char*)d_ws;
  u16*   W1aT  = (u16*)(ws + 16777216);          // 131072
  u16*   W1bT  = (u16*)(ws + 16908288);          // 262144
  u16*   W2T   = (u16*)(ws + 17170432);          // 131072
  float* wq_g  = (float*)(ws + 17301504);        // 393216
  int*   iq_g  = (int*)(ws + 17694720);          // 393216
  float* G     = (float*)(ws + 18087936);        // 8388608

  knn_wconv_kernel<<<192, 1024, 0, stream>>>(xyz_hi, xyz_lo, W1, W2,
                                             wq_g, iq_g, W1aT, W1bT, W2T);
  ggemm_kernel<<<(BB * SS) / 32 * 2, 256, 0, stream>>>(feat_lo, W1bT, G);
  gemm12_kernel<<<MTOT / 64, 256, 0, stream>>>(feat_skip, W1aT, b1, G, wq_g, iq_g,
                                               W2T, b2, gamma, beta, out);
}

// Round 8
// 182.353 us; speedup vs baseline: 1.1267x; 1.1267x over previous
//
#include <hip/hip_runtime.h>
#include <hip/hip_bf16.h>
#include <stdint.h>

typedef unsigned short u16;
typedef __attribute__((ext_vector_type(8))) short short8;
typedef __attribute__((ext_vector_type(4))) float f32x4;

#define BB 4
#define NN 8192
#define SS 2048
#define MTOT 32768
#define CSKIP 256
#define CLO 512
#define CIN 768
#define COUT 256

__device__ __forceinline__ u16 f2bf(float f) {
  unsigned u = __float_as_uint(f);
  u += 0x7fffu + ((u >> 16) & 1u);
  return (u16)(u >> 16);
}

__device__ __forceinline__ void gl_lds16(const void* g, void* l) {
  __builtin_amdgcn_global_load_lds(
      (const __attribute__((address_space(1))) void*)g,
      (__attribute__((address_space(3))) void*)l, 16, 0, 0);
}

// convert 8 consecutive fp32 -> one 16B bf16 chunk
__device__ __forceinline__ void conv_chunk(const float* s, u16* d) {
  union { u16 a[8]; short8 v; } pk;
#pragma unroll
  for (int i = 0; i < 8; ++i) pk.a[i] = f2bf(s[i]);
  *(short8*)d = pk.v;
}

// ---------------------------------------------------------------------------
// K1: 640 blocks x 1024 thr, interleaved roles (blk%5==4 -> wconv, else knn).
//   knn (512 blocks): R5-exact. 64 queries/block, 16 waves x 128 candidates,
//     lane = query, wave-uniform candidate loads, branchless min/med3 insert,
//     diff-form fp32 distances. (R7 lesson: 512-long partitions / 192-block
//     grids kill machine+SIMD occupancy -> 64 us. Reverted.)
//   wconv (128 blocks): weight transposes (W1aT/W1bT/W2T) PLUS bf16
//     pre-conversion of feat_skip & feat_lo into [kc][row][chunk] layout with
//     chunk-position swizzle p = c ^ (row&3). This moves the fp32->bf16 A
//     pack OFF both GEMMs' barrier-locked kc critical paths; staging becomes
//     one linear global_load_lds. Rides under knn's VALU-bound blocks (HBM
//     idle there). Consumers are in later kernels -> race-free.
// ---------------------------------------------------------------------------
__global__ __launch_bounds__(1024) void knn_wconv_kernel(
    const float* __restrict__ xyz_hi, const float* __restrict__ xyz_lo,
    const float* __restrict__ W1, const float* __restrict__ W2,
    const float* __restrict__ feat_skip, const float* __restrict__ feat_lo,
    float* __restrict__ wq_g, int* __restrict__ iq_g,
    u16* __restrict__ W1aT, u16* __restrict__ W1bT, u16* __restrict__ W2T,
    u16* __restrict__ FSB, u16* __restrict__ FLB) {
  int blk = blockIdx.x;
  int tid = threadIdx.x;

  if ((blk % 5) == 4) {
    // ---- wconv: 128 blocks x 1024 thr = 131072 threads ----
    int wtid = (blk / 5) * 1024 + tid;
    // feat_skip -> FSB[kc8][row32768][p4] (8 bf16 per chunk), p = c^(row&3)
    for (int t = wtid; t < 1048576; t += 131072) {
      int p = t & 3, r = (t >> 2) & 32767, kc = t >> 17;
      int c = p ^ (r & 3);
      conv_chunk(feat_skip + (size_t)r * CSKIP + kc * 32 + c * 8,
                 FSB + (size_t)t * 8);
    }
    // feat_lo -> FLB[kc16][row8192][p4]
    for (int t = wtid; t < 524288; t += 131072) {
      int p = t & 3, r = (t >> 2) & 8191, kc = t >> 15;
      int c = p ^ (r & 3);
      conv_chunk(feat_lo + (size_t)r * CLO + kc * 32 + c * 8,
                 FLB + (size_t)t * 8);
    }
    // weight transposes (as before)
    for (int i = wtid; i < 262144; i += 131072) {
      if (i < 65536) {                       // W1aT: n=i>>8, k=i&255
        int n = i >> 8, k = i & 255;
        W1aT[i] = f2bf(W1[(size_t)k * COUT + n]);
      } else if (i < 196608) {               // W1bT: n=j>>9, k=j&511
        int j = i - 65536;
        int n = j >> 9, k = j & 511;
        W1bT[j] = f2bf(W1[(size_t)(256 + k) * COUT + n]);
      } else {                               // W2T
        int j = i - 196608;
        int n = j >> 8, k = j & 255;
        W2T[j] = f2bf(W2[(size_t)k * COUT + n]);
      }
    }
    return;
  }

  // ---- knn (R5-exact) ----
  __shared__ float md[16][64][3];
  __shared__ int   mi[16][64][3];

  int kblk = (blk / 5) * 4 + (blk % 5);      // 0..511
  int b = kblk >> 7;
  int wave = tid >> 6, lane = tid & 63;
  int qm = kblk * 64 + lane;
  float qx = xyz_hi[(size_t)qm * 3 + 0];
  float qy = xyz_hi[(size_t)qm * 3 + 1];
  float qz = xyz_hi[(size_t)qm * 3 + 2];

  const float* xl = xyz_lo + (size_t)b * SS * 3;
  int j0 = __builtin_amdgcn_readfirstlane(wave * 128);

  float b0 = 1e30f, b1 = 1e30f, b2 = 1e30f;
  int i0 = -1, i1 = -1, i2 = -1;
#pragma unroll 8
  for (int jj = 0; jj < 128; ++jj) {
    int j = j0 + jj;
    float px = xl[3 * j + 0];            // uniform -> scalar load / broadcast
    float py = xl[3 * j + 1];
    float pz = xl[3 * j + 2];
    float dx = px - qx, dy = py - qy, dz = pz - qz;
    float d = fmaf(dx, dx, fmaf(dy, dy, dz * dz));
    bool c0 = d < b0, c1 = d < b1, c2 = d < b2;
    float nb0 = fminf(b0, d);
    float nb1 = __builtin_amdgcn_fmed3f(b0, b1, d);
    float nb2 = __builtin_amdgcn_fmed3f(b1, b2, d);
    int ni0 = c0 ? j : i0;
    int ni1 = c0 ? i0 : (c1 ? j : i1);
    int ni2 = c1 ? i1 : (c2 ? j : i2);
    b0 = nb0; b1 = nb1; b2 = nb2;
    i0 = ni0; i1 = ni1; i2 = ni2;
  }
  md[wave][lane][0] = b0; mi[wave][lane][0] = i0;
  md[wave][lane][1] = b1; mi[wave][lane][1] = i1;
  md[wave][lane][2] = b2; mi[wave][lane][2] = i2;
  __syncthreads();

  if (tid < 64) {
    int q = tid;
    float fb0 = 1e30f, fb1 = 1e30f, fb2 = 1e30f;
    int fi0 = -1, fi1 = -1, fi2 = -1;
    // parts are contiguous ascending ranges; merge with index tiebreak
    for (int p = 0; p < 16; ++p)
#pragma unroll
      for (int s = 0; s < 3; ++s) {
        float d = md[p][q][s]; int ix = mi[p][q][s];
        if (d < fb2 || (d == fb2 && ix < fi2)) {
          fb2 = d; fi2 = ix;
          if (fb2 < fb1 || (fb2 == fb1 && fi2 < fi1)) {
            float t = fb1; fb1 = fb2; fb2 = t; int ti = fi1; fi1 = fi2; fi2 = ti;
          }
          if (fb1 < fb0 || (fb1 == fb0 && fi1 < fi0)) {
            float t = fb0; fb0 = fb1; fb1 = t; int ti = fi0; fi0 = fi1; fi1 = ti;
          }
        }
      }
    int qm2 = kblk * 64 + q;
    float d0 = sqrtf(fb0), d1 = sqrtf(fb1), d2 = sqrtf(fb2);
    float inv0 = 1.0f / (d0 + 1e-8f);
    float inv1 = 1.0f / (d1 + 1e-8f);
    float inv2 = 1.0f / (d2 + 1e-8f);
    float s = inv0 + inv1 + inv2;
    wq_g[(size_t)qm2 * 3 + 0] = inv0 / s;
    wq_g[(size_t)qm2 * 3 + 1] = inv1 / s;
    wq_g[(size_t)qm2 * 3 + 2] = inv2 / s;
    iq_g[(size_t)qm2 * 3 + 0] = fi0;
    iq_g[(size_t)qm2 * 3 + 1] = fi1;
    iq_g[(size_t)qm2 * 3 + 2] = fi2;
  }
}

// ---------------------------------------------------------------------------
// K2: ggemm — G = feat_lo @ W1b  (dense, M=8192, K=512, N=256, fp32 out).
// Tile 32x128, 256 thr, BK=32, grid 512 -> 4 blocks/CU, dbuf 1 barrier/kc.
// R8: A staged from pre-converted FLB via ONE linear gl_lds16 (tid<128) —
// no fp32 load, no pack, no VALU on the A path. Frag reads use the same
// quad^(row&3) swizzle formula as the proven B path.
// ---------------------------------------------------------------------------
__global__ __launch_bounds__(256, 4) void ggemm_kernel(
    const u16* __restrict__ FLB, const u16* __restrict__ W1bT,
    float* __restrict__ G) {
  __shared__ u16 As[2][32 * 32];
  __shared__ u16 Bs[2][128 * 32];
  int tid = threadIdx.x;
  int m0 = (blockIdx.x >> 1) << 5;
  int n0 = (blockIdx.x & 1) << 7;
  int w = tid >> 6, lane = tid & 63;
  int quad = lane >> 4, l16 = lane & 15;

  f32x4 zero = {0.f, 0.f, 0.f, 0.f};
  f32x4 acc[2][2];
#pragma unroll
  for (int tm = 0; tm < 2; ++tm)
#pragma unroll
    for (int tn = 0; tn < 2; ++tn) acc[tm][tn] = zero;

  auto stageA = [&](u16* An, int kc) {
    if (tid < 128)
      gl_lds16((const char*)(FLB + ((size_t)kc * NN + m0) * 32) + tid * 16,
               (char*)An + tid * 16);
  };
  auto stageB = [&](u16* Bn, int kc) {
#pragma unroll
    for (int r = 0; r < 2; ++r) {
      int u = tid + r * 256;
      int nrow = u >> 2, c = u & 3;
      int cg = c ^ (nrow & 3);
      gl_lds16(W1bT + (size_t)(n0 + nrow) * CLO + kc * 32 + cg * 8,
               (char*)Bn + u * 16);
    }
  };

  stageB(Bs[0], 0);
  stageA(As[0], 0);

  for (int kc = 0; kc < 16; ++kc) {
    __syncthreads();             // buf[cur] staged+visible; buf[nxt] reads done
    const u16* Ac = As[kc & 1];
    const u16* Bc = Bs[kc & 1];
    if (kc + 1 < 16) {
      stageB(Bs[(kc + 1) & 1], kc + 1);
      stageA(As[(kc + 1) & 1], kc + 1);
    }

    short8 af[2], bf[2];
#pragma unroll
    for (int t = 0; t < 2; ++t) {
      int rr = t * 16 + l16;
      af[t] = *(const short8*)(Ac + (rr * 4 + (quad ^ (rr & 3))) * 8);
    }
#pragma unroll
    for (int t = 0; t < 2; ++t) {
      int rr = w * 32 + t * 16 + l16;
      bf[t] = *(const short8*)(Bc + (rr * 4 + (quad ^ (rr & 3))) * 8);
    }
#pragma unroll
    for (int tm = 0; tm < 2; ++tm)
#pragma unroll
      for (int tn = 0; tn < 2; ++tn)
        acc[tm][tn] = __builtin_amdgcn_mfma_f32_16x16x32_bf16(af[tm], bf[tn], acc[tm][tn], 0, 0, 0);
  }

#pragma unroll
  for (int tm = 0; tm < 2; ++tm)
#pragma unroll
    for (int tn = 0; tn < 2; ++tn) {
      int col = n0 + w * 32 + tn * 16 + l16;
#pragma unroll
      for (int r = 0; r < 4; ++r) {
        int row = m0 + tm * 16 + quad * 4 + r;
        G[(size_t)row * COUT + col] = acc[tm][tn][r];
      }
    }
}

// ---------------------------------------------------------------------------
// K3: fused MLP — phase 1: Htile = relu(skip@W1a + b1 + IDW-gather(G)) -> LDS
// (bf16, rows padded to 264); phase 2: out = LN(Htile@W2 + b2).
// R5 structure (64-row tile, serial-tail gather, both phases dbuf, 1
// barrier/kc) with R8's A-path: As staged from pre-converted FSB via one
// linear gl_lds16/thread — removes the HBM-load->cvt->pack VALU stall from
// every kc. LDS 78848 -> still 2 blocks/CU.
// ---------------------------------------------------------------------------
__global__ __launch_bounds__(256, 2) void gemm12_kernel(
    const u16* __restrict__ FSB, const u16* __restrict__ W1aT,
    const float* __restrict__ b1, const float* __restrict__ G,
    const float* __restrict__ wq_g, const int* __restrict__ iq_g,
    const u16* __restrict__ W2T, const float* __restrict__ b2,
    const float* __restrict__ gamma, const float* __restrict__ beta,
    float* __restrict__ out) {
  __shared__ u16 Hs[64 * 264];
  __shared__ u16 Bs[256 * 32];
  __shared__ u16 Bs2[256 * 32];
  __shared__ u16 As[2][64 * 32];
  __shared__ float swq[192];
  __shared__ int   siq[192];
  __shared__ float red[4][64][2];
  __shared__ float stats[64][2];
  int tid = threadIdx.x;
  int m0 = blockIdx.x << 6;
  int bS = (m0 >> 13) * SS;
  int w = tid >> 6, lane = tid & 63;
  int quad = lane >> 4, l16 = lane & 15;

  if (tid < 192) {
    swq[tid] = wq_g[(size_t)m0 * 3 + tid];
    siq[tid] = iq_g[(size_t)m0 * 3 + tid];
  }

  f32x4 zero = {0.f, 0.f, 0.f, 0.f};
  f32x4 acc[4][4];
#pragma unroll
  for (int tm = 0; tm < 4; ++tm)
#pragma unroll
    for (int tn = 0; tn < 4; ++tn) acc[tm][tn] = zero;

  auto stageA = [&](u16* An, int kc) {
    gl_lds16((const char*)(FSB + ((size_t)kc * MTOT + m0) * 32) + tid * 16,
             (char*)An + tid * 16);
  };

  // ---- phase 1 prologue: stage kc=0 (Bs <- W1aT, As[0] <- FSB) ----
#pragma unroll
  for (int r = 0; r < 4; ++r) {
    int u = tid + r * 256;
    int nrow = u >> 2, c = u & 3;
    int cg = c ^ (nrow & 3);
    gl_lds16(W1aT + (size_t)nrow * CSKIP + cg * 8, (char*)Bs + u * 16);
  }
  stageA(As[0], 0);

  // ---- phase 1: skip @ W1a — double-buffered, 1 barrier/kc ----
  for (int kc = 0; kc < 8; ++kc) {
    __syncthreads();             // buf[cur] staged+visible; buf[nxt] reads done
    const u16* Ac = As[kc & 1];
    u16* Bc = (kc & 1) ? Bs2 : Bs;
    if (kc + 1 < 8) {
      u16* Bn = (kc & 1) ? Bs : Bs2;
#pragma unroll
      for (int r = 0; r < 4; ++r) {
        int u = tid + r * 256;
        int nrow = u >> 2, c = u & 3;
        int cg = c ^ (nrow & 3);
        gl_lds16(W1aT + (size_t)nrow * CSKIP + (kc + 1) * 32 + cg * 8,
                 (char*)Bn + u * 16);
      }
      stageA(As[(kc + 1) & 1], kc + 1);
    }

    short8 af[4], bf[4];
#pragma unroll
    for (int t = 0; t < 4; ++t) {
      int rr = t * 16 + l16;
      af[t] = *(const short8*)(Ac + (rr * 4 + (quad ^ (rr & 3))) * 8);
    }
#pragma unroll
    for (int t = 0; t < 4; ++t) {
      int rr = w * 64 + t * 16 + l16;
      bf[t] = *(const short8*)(Bc + (rr * 4 + (quad ^ (rr & 3))) * 8);
    }
#pragma unroll
    for (int tm = 0; tm < 4; ++tm)
#pragma unroll
      for (int tn = 0; tn < 4; ++tn)
        acc[tm][tn] = __builtin_amdgcn_mfma_f32_16x16x32_bf16(af[tm], bf[tn], acc[tm][tn], 0, 0, 0);
  }

  // ---- phase 1 epilogue: bias + serial IDW gather + relu -> Hs ----
  {
    float bias[4];
#pragma unroll
    for (int tn = 0; tn < 4; ++tn) bias[tn] = b1[w * 64 + tn * 16 + l16];
#pragma unroll
    for (int tm = 0; tm < 4; ++tm)
#pragma unroll
      for (int r = 0; r < 4; ++r) {
        int rl = tm * 16 + quad * 4 + r;
        float w0 = swq[rl * 3 + 0], w1 = swq[rl * 3 + 1], w2 = swq[rl * 3 + 2];
        const float* g0 = G + (size_t)(bS + siq[rl * 3 + 0]) * COUT;
        const float* g1 = G + (size_t)(bS + siq[rl * 3 + 1]) * COUT;
        const float* g2 = G + (size_t)(bS + siq[rl * 3 + 2]) * COUT;
#pragma unroll
        for (int tn = 0; tn < 4; ++tn) {
          int col = w * 64 + tn * 16 + l16;
          float gv = fmaf(w0, g0[col], fmaf(w1, g1[col], w2 * g2[col]));
          float v = acc[tm][tn][r] + bias[tn] + gv;
          v = v > 0.f ? v : 0.f;
          Hs[rl * 264 + col] = f2bf(v);
        }
      }
  }

  // ---- phase 2: Hs @ W2 + LN, double-buffered B, 1 barrier/iter ----
#pragma unroll
  for (int tm = 0; tm < 4; ++tm)
#pragma unroll
    for (int tn = 0; tn < 4; ++tn) acc[tm][tn] = zero;

  __syncthreads();               // Hs writes visible; phase-1 Bs reads done
#pragma unroll
  for (int r = 0; r < 4; ++r) {  // stage kc=0 into Bs
    int u = tid + r * 256;
    int nrow = u >> 2, c = u & 3;
    int cg = c ^ (nrow & 3);
    gl_lds16(W2T + (size_t)nrow * COUT + cg * 8, (char*)Bs + u * 16);
  }
  for (int kc = 0; kc < 8; ++kc) {
    __syncthreads();             // B(kc) staged (vmcnt drained at barrier)
    u16* cur = (kc & 1) ? Bs2 : Bs;
    u16* nxt = (kc & 1) ? Bs : Bs2;
    if (kc + 1 < 8) {
#pragma unroll
      for (int r = 0; r < 4; ++r) {
        int u = tid + r * 256;
        int nrow = u >> 2, c = u & 3;
        int cg = c ^ (nrow & 3);
        gl_lds16(W2T + (size_t)nrow * COUT + (kc + 1) * 32 + cg * 8,
                 (char*)nxt + u * 16);
      }
    }
    short8 af[4], bf[4];
#pragma unroll
    for (int t = 0; t < 4; ++t)
      af[t] = *(const short8*)(Hs + (t * 16 + l16) * 264 + kc * 32 + quad * 8);
#pragma unroll
    for (int t = 0; t < 4; ++t) {
      int rr = w * 64 + t * 16 + l16;
      bf[t] = *(const short8*)(cur + (rr * 4 + (quad ^ (rr & 3))) * 8);
    }
#pragma unroll
    for (int tm = 0; tm < 4; ++tm)
#pragma unroll
      for (int tn = 0; tn < 4; ++tn)
        acc[tm][tn] = __builtin_amdgcn_mfma_f32_16x16x32_bf16(af[tm], bf[tn], acc[tm][tn], 0, 0, 0);
  }

  float bias[4], g[4], be[4];
#pragma unroll
  for (int tn = 0; tn < 4; ++tn) {
    int col = w * 64 + tn * 16 + l16;
    bias[tn] = b2[col]; g[tn] = gamma[col]; be[tn] = beta[col];
  }
#pragma unroll
  for (int tm = 0; tm < 4; ++tm)
#pragma unroll
    for (int r = 0; r < 4; ++r) {
      float s = 0.f, sq = 0.f;
#pragma unroll
      for (int tn = 0; tn < 4; ++tn) {
        float v = acc[tm][tn][r] + bias[tn];
        acc[tm][tn][r] = v;
        s += v; sq += v * v;
      }
#pragma unroll
      for (int msk = 1; msk < 16; msk <<= 1) {
        s += __shfl_xor(s, msk);
        sq += __shfl_xor(sq, msk);
      }
      if (l16 == 0) {
        int rl = tm * 16 + quad * 4 + r;
        red[w][rl][0] = s;
        red[w][rl][1] = sq;
      }
    }
  __syncthreads();
  if (tid < 64) {
    float s = red[0][tid][0] + red[1][tid][0] + red[2][tid][0] + red[3][tid][0];
    float sq = red[0][tid][1] + red[1][tid][1] + red[2][tid][1] + red[3][tid][1];
    float mu = s * (1.f / 256.f);
    float var = sq * (1.f / 256.f) - mu * mu;
    stats[tid][0] = mu;
    stats[tid][1] = rsqrtf(var + 1e-5f);
  }
  __syncthreads();
#pragma unroll
  for (int tm = 0; tm < 4; ++tm)
#pragma unroll
    for (int r = 0; r < 4; ++r) {
      int rl = tm * 16 + quad * 4 + r;
      float mu = stats[rl][0], rstd = stats[rl][1];
#pragma unroll
      for (int tn = 0; tn < 4; ++tn) {
        int col = w * 64 + tn * 16 + l16;
        out[(size_t)(m0 + rl) * COUT + col] = (acc[tm][tn][r] - mu) * rstd * g[tn] + be[tn];
      }
    }
}

// ---------------------------------------------------------------------------
extern "C" void kernel_launch(void* const* d_in, const int* in_sizes, int n_in,
                              void* d_out, int out_size, void* d_ws, size_t ws_size,
                              hipStream_t stream) {
  const float* xyz_hi    = (const float*)d_in[0];
  const float* xyz_lo    = (const float*)d_in[1];
  const float* feat_skip = (const float*)d_in[2];
  const float* feat_lo   = (const float*)d_in[3];
  const float* W1        = (const float*)d_in[4];
  const float* b1        = (const float*)d_in[5];
  const float* W2        = (const float*)d_in[6];
  const float* b2        = (const float*)d_in[7];
  const float* gamma     = (const float*)d_in[8];
  const float* beta      = (const float*)d_in[9];
  float* out = (float*)d_out;

  char* ws = (char*)d_ws;
  u16*   FSB   = (u16*)(ws + 0);                 // 16777216 (feat_skip bf16)
  u16*   W1aT  = (u16*)(ws + 16777216);          // 131072
  u16*   W1bT  = (u16*)(ws + 16908288);          // 262144
  u16*   W2T   = (u16*)(ws + 17170432);          // 131072
  float* wq_g  = (float*)(ws + 17301504);        // 393216
  int*   iq_g  = (int*)(ws + 17694720);          // 393216
  float* G     = (float*)(ws + 18087936);        // 8388608
  u16*   FLB   = (u16*)(ws + 26476544);          // 8388608 (feat_lo bf16)

  knn_wconv_kernel<<<640, 1024, 0, stream>>>(xyz_hi, xyz_lo, W1, W2,
                                             feat_skip, feat_lo,
                                             wq_g, iq_g, W1aT, W1bT, W2T,
                                             FSB, FLB);
  ggemm_kernel<<<(BB * SS) / 32 * 2, 256, 0, stream>>>(FLB, W1bT, G);
  gemm12_kernel<<<MTOT / 64, 256, 0, stream>>>(FSB, W1aT, b1, G, wq_g, iq_g,
                                               W2T, b2, gamma, beta, out);
}

// Round 9
// 174.310 us; speedup vs baseline: 1.1787x; 1.0461x over previous
//
#include <hip/hip_runtime.h>
#include <hip/hip_bf16.h>
#include <stdint.h>

typedef unsigned short u16;
typedef __attribute__((ext_vector_type(8))) short short8;
typedef __attribute__((ext_vector_type(4))) float f32x4;

#define BB 4
#define NN 8192
#define SS 2048
#define MTOT 32768
#define CSKIP 256
#define CLO 512
#define CIN 768
#define COUT 256

__device__ __forceinline__ u16 f2bf(float f) {
  unsigned u = __float_as_uint(f);
  u += 0x7fffu + ((u >> 16) & 1u);
  return (u16)(u >> 16);
}

__device__ __forceinline__ void gl_lds16(const void* g, void* l) {
  __builtin_amdgcn_global_load_lds(
      (const __attribute__((address_space(1))) void*)g,
      (__attribute__((address_space(3))) void*)l, 16, 0, 0);
}

__device__ __forceinline__ void pack_store(u16* d, float4 x0, float4 x1) {
  union { u16 a[8]; short8 v; } pk;
  pk.a[0] = f2bf(x0.x); pk.a[1] = f2bf(x0.y);
  pk.a[2] = f2bf(x0.z); pk.a[3] = f2bf(x0.w);
  pk.a[4] = f2bf(x1.x); pk.a[5] = f2bf(x1.y);
  pk.a[6] = f2bf(x1.z); pk.a[7] = f2bf(x1.w);
  *(short8*)d = pk.v;
}

// ---------------------------------------------------------------------------
// K1: grid 576.
//   blocks 0..511: KNN (R5-exact VALU structure) + feat bf16 conversion
//     overlapped: each thread owns 3 chunks (2 FSB + 1 FLB) of the
//     [kc][row][p] layout (p = c ^ (row&3)); the 6 float4 source loads are
//     issued BEFORE the knn loop (no vector-mem ops inside it -> they stay
//     in flight under the ~37 us VALU-bound phase, using idle HBM BW), and
//     the pack+store tail (24 MB machine-wide ~ 4 us) runs after the merge.
//     R8 lesson: conversion on 128 dedicated blocks = 1/5 machine BW = 55 us
//     serial tail. Spreading it over all 512 knn blocks overlaps it.
//   blocks 512..575: weight transposes (W1aT/W1bT/W2T), as R5.
// Consumers of FSB/FLB/W*T are in later kernels -> race-free.
// ---------------------------------------------------------------------------
__global__ __launch_bounds__(1024) void knn_wconv_kernel(
    const float* __restrict__ xyz_hi, const float* __restrict__ xyz_lo,
    const float* __restrict__ W1, const float* __restrict__ W2,
    const float* __restrict__ feat_skip, const float* __restrict__ feat_lo,
    float* __restrict__ wq_g, int* __restrict__ iq_g,
    u16* __restrict__ W1aT, u16* __restrict__ W1bT, u16* __restrict__ W2T,
    u16* __restrict__ FSB, u16* __restrict__ FLB) {
  int blk = blockIdx.x;
  int tid = threadIdx.x;

  if (blk >= 512) {
    // ---- wconv: 262144 weight elems over 64 blocks x 1024 thr ----
    int base = (blk - 512) * 1024 + tid;
    for (int i = base; i < 262144; i += 65536) {
      if (i < 65536) {                       // W1aT: n=i>>8, k=i&255
        int n = i >> 8, k = i & 255;
        W1aT[i] = f2bf(W1[(size_t)k * COUT + n]);
      } else if (i < 196608) {               // W1bT: n=j>>9, k=j&511
        int j = i - 65536;
        int n = j >> 9, k = j & 511;
        W1bT[j] = f2bf(W1[(size_t)(256 + k) * COUT + n]);
      } else {                               // W2T
        int j = i - 196608;
        int n = j >> 8, k = j & 255;
        W2T[j] = f2bf(W2[(size_t)k * COUT + n]);
      }
    }
    return;
  }

  // ---- knn block: early-issue conversion loads (overlap knn VALU) ----
  int wtid = blk * 1024 + tid;               // 0..524287
  // FSB chunk t0 = wtid, t1 = wtid + 524288; FLB chunk u = wtid.
  int t0 = wtid;
  int p0 = t0 & 3, r0 = (t0 >> 2) & 32767, k0 = t0 >> 17;
  const float* s0 = feat_skip + (size_t)r0 * CSKIP + k0 * 32 + (p0 ^ (r0 & 3)) * 8;
  int t1 = wtid + 524288;
  int p1 = t1 & 3, r1 = (t1 >> 2) & 32767, k1 = t1 >> 17;
  const float* s1 = feat_skip + (size_t)r1 * CSKIP + k1 * 32 + (p1 ^ (r1 & 3)) * 8;
  int p2 = wtid & 3, r2 = (wtid >> 2) & 8191, k2 = wtid >> 15;
  const float* s2 = feat_lo + (size_t)r2 * CLO + k2 * 32 + (p2 ^ (r2 & 3)) * 8;
  float4 c0a = *(const float4*)s0, c0b = *(const float4*)(s0 + 4);
  float4 c1a = *(const float4*)s1, c1b = *(const float4*)(s1 + 4);
  float4 c2a = *(const float4*)s2, c2b = *(const float4*)(s2 + 4);

  // ---- knn (R5-exact) ----
  __shared__ float md[16][64][3];
  __shared__ int   mi[16][64][3];

  int b = blk >> 7;
  int wave = tid >> 6, lane = tid & 63;
  int qm = blk * 64 + lane;
  float qx = xyz_hi[(size_t)qm * 3 + 0];
  float qy = xyz_hi[(size_t)qm * 3 + 1];
  float qz = xyz_hi[(size_t)qm * 3 + 2];

  const float* xl = xyz_lo + (size_t)b * SS * 3;
  int j0 = __builtin_amdgcn_readfirstlane(wave * 128);

  float b0 = 1e30f, b1 = 1e30f, b2 = 1e30f;
  int i0 = -1, i1 = -1, i2 = -1;
#pragma unroll 8
  for (int jj = 0; jj < 128; ++jj) {
    int j = j0 + jj;
    float px = xl[3 * j + 0];            // uniform -> scalar load / broadcast
    float py = xl[3 * j + 1];
    float pz = xl[3 * j + 2];
    float dx = px - qx, dy = py - qy, dz = pz - qz;
    float d = fmaf(dx, dx, fmaf(dy, dy, dz * dz));
    bool c0 = d < b0, c1 = d < b1, c2 = d < b2;
    float nb0 = fminf(b0, d);
    float nb1 = __builtin_amdgcn_fmed3f(b0, b1, d);
    float nb2 = __builtin_amdgcn_fmed3f(b1, b2, d);
    int ni0 = c0 ? j : i0;
    int ni1 = c0 ? i0 : (c1 ? j : i1);
    int ni2 = c1 ? i1 : (c2 ? j : i2);
    b0 = nb0; b1 = nb1; b2 = nb2;
    i0 = ni0; i1 = ni1; i2 = ni2;
  }
  md[wave][lane][0] = b0; mi[wave][lane][0] = i0;
  md[wave][lane][1] = b1; mi[wave][lane][1] = i1;
  md[wave][lane][2] = b2; mi[wave][lane][2] = i2;
  __syncthreads();

  if (tid < 64) {
    int q = tid;
    float fb0 = 1e30f, fb1 = 1e30f, fb2 = 1e30f;
    int fi0 = -1, fi1 = -1, fi2 = -1;
    // parts are contiguous ascending ranges; merge with index tiebreak
    for (int p = 0; p < 16; ++p)
#pragma unroll
      for (int s = 0; s < 3; ++s) {
        float d = md[p][q][s]; int ix = mi[p][q][s];
        if (d < fb2 || (d == fb2 && ix < fi2)) {
          fb2 = d; fi2 = ix;
          if (fb2 < fb1 || (fb2 == fb1 && fi2 < fi1)) {
            float t = fb1; fb1 = fb2; fb2 = t; int ti = fi1; fi1 = fi2; fi2 = ti;
          }
          if (fb1 < fb0 || (fb1 == fb0 && fi1 < fi0)) {
            float t = fb0; fb0 = fb1; fb1 = t; int ti = fi0; fi0 = fi1; fi1 = ti;
          }
        }
      }
    int qm2 = blk * 64 + q;
    float d0 = sqrtf(fb0), d1 = sqrtf(fb1), d2 = sqrtf(fb2);
    float inv0 = 1.0f / (d0 + 1e-8f);
    float inv1 = 1.0f / (d1 + 1e-8f);
    float inv2 = 1.0f / (d2 + 1e-8f);
    float s = inv0 + inv1 + inv2;
    wq_g[(size_t)qm2 * 3 + 0] = inv0 / s;
    wq_g[(size_t)qm2 * 3 + 1] = inv1 / s;
    wq_g[(size_t)qm2 * 3 + 2] = inv2 / s;
    iq_g[(size_t)qm2 * 3 + 0] = fi0;
    iq_g[(size_t)qm2 * 3 + 1] = fi1;
    iq_g[(size_t)qm2 * 3 + 2] = fi2;
  }

  // ---- conversion tail: pack + store (data arrived during knn phase) ----
  pack_store(FSB + (size_t)t0 * 8, c0a, c0b);
  pack_store(FSB + (size_t)t1 * 8, c1a, c1b);
  pack_store(FLB + (size_t)wtid * 8, c2a, c2b);
}

// ---------------------------------------------------------------------------
// K2: ggemm — G = feat_lo @ W1b  (dense, M=8192, K=512, N=256, fp32 out).
// Tile 32x128, 256 thr, BK=32, grid 512 -> 4 blocks/CU, dbuf 1 barrier/kc.
// A staged from pre-converted FLB via ONE linear gl_lds16 (tid<128).
// (R8-measured ~10.5 us; unchanged.)
// ---------------------------------------------------------------------------
__global__ __launch_bounds__(256, 4) void ggemm_kernel(
    const u16* __restrict__ FLB, const u16* __restrict__ W1bT,
    float* __restrict__ G) {
  __shared__ u16 As[2][32 * 32];
  __shared__ u16 Bs[2][128 * 32];
  int tid = threadIdx.x;
  int m0 = (blockIdx.x >> 1) << 5;
  int n0 = (blockIdx.x & 1) << 7;
  int w = tid >> 6, lane = tid & 63;
  int quad = lane >> 4, l16 = lane & 15;

  f32x4 zero = {0.f, 0.f, 0.f, 0.f};
  f32x4 acc[2][2];
#pragma unroll
  for (int tm = 0; tm < 2; ++tm)
#pragma unroll
    for (int tn = 0; tn < 2; ++tn) acc[tm][tn] = zero;

  auto stageA = [&](u16* An, int kc) {
    if (tid < 128)
      gl_lds16((const char*)(FLB + ((size_t)kc * NN + m0) * 32) + tid * 16,
               (char*)An + tid * 16);
  };
  auto stageB = [&](u16* Bn, int kc) {
#pragma unroll
    for (int r = 0; r < 2; ++r) {
      int u = tid + r * 256;
      int nrow = u >> 2, c = u & 3;
      int cg = c ^ (nrow & 3);
      gl_lds16(W1bT + (size_t)(n0 + nrow) * CLO + kc * 32 + cg * 8,
               (char*)Bn + u * 16);
    }
  };

  stageB(Bs[0], 0);
  stageA(As[0], 0);

  for (int kc = 0; kc < 16; ++kc) {
    __syncthreads();             // buf[cur] staged+visible; buf[nxt] reads done
    const u16* Ac = As[kc & 1];
    const u16* Bc = Bs[kc & 1];
    if (kc + 1 < 16) {
      stageB(Bs[(kc + 1) & 1], kc + 1);
      stageA(As[(kc + 1) & 1], kc + 1);
    }

    short8 af[2], bf[2];
#pragma unroll
    for (int t = 0; t < 2; ++t) {
      int rr = t * 16 + l16;
      af[t] = *(const short8*)(Ac + (rr * 4 + (quad ^ (rr & 3))) * 8);
    }
#pragma unroll
    for (int t = 0; t < 2; ++t) {
      int rr = w * 32 + t * 16 + l16;
      bf[t] = *(const short8*)(Bc + (rr * 4 + (quad ^ (rr & 3))) * 8);
    }
#pragma unroll
    for (int tm = 0; tm < 2; ++tm)
#pragma unroll
      for (int tn = 0; tn < 2; ++tn)
        acc[tm][tn] = __builtin_amdgcn_mfma_f32_16x16x32_bf16(af[tm], bf[tn], acc[tm][tn], 0, 0, 0);
  }

#pragma unroll
  for (int tm = 0; tm < 2; ++tm)
#pragma unroll
    for (int tn = 0; tn < 2; ++tn) {
      int col = n0 + w * 32 + tn * 16 + l16;
#pragma unroll
      for (int r = 0; r < 4; ++r) {
        int row = m0 + tm * 16 + quad * 4 + r;
        G[(size_t)row * COUT + col] = acc[tm][tn][r];
      }
    }
}

// ---------------------------------------------------------------------------
// K3: fused MLP — phase 1: Htile = relu(skip@W1a + b1 + IDW-gather(G)) -> LDS
// (bf16, rows padded to 264); phase 2: out = LN(Htile@W2 + b2).
// 64-row tile, serial-tail gather, both phases dbuf, 1 barrier/kc; As staged
// from pre-converted FSB via one linear gl_lds16/thread.
// (R8-measured ~27 us; unchanged.)
// ---------------------------------------------------------------------------
__global__ __launch_bounds__(256, 2) void gemm12_kernel(
    const u16* __restrict__ FSB, const u16* __restrict__ W1aT,
    const float* __restrict__ b1, const float* __restrict__ G,
    const float* __restrict__ wq_g, const int* __restrict__ iq_g,
    const u16* __restrict__ W2T, const float* __restrict__ b2,
    const float* __restrict__ gamma, const float* __restrict__ beta,
    float* __restrict__ out) {
  __shared__ u16 Hs[64 * 264];
  __shared__ u16 Bs[256 * 32];
  __shared__ u16 Bs2[256 * 32];
  __shared__ u16 As[2][64 * 32];
  __shared__ float swq[192];
  __shared__ int   siq[192];
  __shared__ float red[4][64][2];
  __shared__ float stats[64][2];
  int tid = threadIdx.x;
  int m0 = blockIdx.x << 6;
  int bS = (m0 >> 13) * SS;
  int w = tid >> 6, lane = tid & 63;
  int quad = lane >> 4, l16 = lane & 15;

  if (tid < 192) {
    swq[tid] = wq_g[(size_t)m0 * 3 + tid];
    siq[tid] = iq_g[(size_t)m0 * 3 + tid];
  }

  f32x4 zero = {0.f, 0.f, 0.f, 0.f};
  f32x4 acc[4][4];
#pragma unroll
  for (int tm = 0; tm < 4; ++tm)
#pragma unroll
    for (int tn = 0; tn < 4; ++tn) acc[tm][tn] = zero;

  auto stageA = [&](u16* An, int kc) {
    gl_lds16((const char*)(FSB + ((size_t)kc * MTOT + m0) * 32) + tid * 16,
             (char*)An + tid * 16);
  };

  // ---- phase 1 prologue: stage kc=0 (Bs <- W1aT, As[0] <- FSB) ----
#pragma unroll
  for (int r = 0; r < 4; ++r) {
    int u = tid + r * 256;
    int nrow = u >> 2, c = u & 3;
    int cg = c ^ (nrow & 3);
    gl_lds16(W1aT + (size_t)nrow * CSKIP + cg * 8, (char*)Bs + u * 16);
  }
  stageA(As[0], 0);

  // ---- phase 1: skip @ W1a — double-buffered, 1 barrier/kc ----
  for (int kc = 0; kc < 8; ++kc) {
    __syncthreads();             // buf[cur] staged+visible; buf[nxt] reads done
    const u16* Ac = As[kc & 1];
    u16* Bc = (kc & 1) ? Bs2 : Bs;
    if (kc + 1 < 8) {
      u16* Bn = (kc & 1) ? Bs : Bs2;
#pragma unroll
      for (int r = 0; r < 4; ++r) {
        int u = tid + r * 256;
        int nrow = u >> 2, c = u & 3;
        int cg = c ^ (nrow & 3);
        gl_lds16(W1aT + (size_t)nrow * CSKIP + (kc + 1) * 32 + cg * 8,
                 (char*)Bn + u * 16);
      }
      stageA(As[(kc + 1) & 1], kc + 1);
    }

    short8 af[4], bf[4];
#pragma unroll
    for (int t = 0; t < 4; ++t) {
      int rr = t * 16 + l16;
      af[t] = *(const short8*)(Ac + (rr * 4 + (quad ^ (rr & 3))) * 8);
    }
#pragma unroll
    for (int t = 0; t < 4; ++t) {
      int rr = w * 64 + t * 16 + l16;
      bf[t] = *(const short8*)(Bc + (rr * 4 + (quad ^ (rr & 3))) * 8);
    }
#pragma unroll
    for (int tm = 0; tm < 4; ++tm)
#pragma unroll
      for (int tn = 0; tn < 4; ++tn)
        acc[tm][tn] = __builtin_amdgcn_mfma_f32_16x16x32_bf16(af[tm], bf[tn], acc[tm][tn], 0, 0, 0);
  }

  // ---- phase 1 epilogue: bias + serial IDW gather + relu -> Hs ----
  {
    float bias[4];
#pragma unroll
    for (int tn = 0; tn < 4; ++tn) bias[tn] = b1[w * 64 + tn * 16 + l16];
#pragma unroll
    for (int tm = 0; tm < 4; ++tm)
#pragma unroll
      for (int r = 0; r < 4; ++r) {
        int rl = tm * 16 + quad * 4 + r;
        float w0 = swq[rl * 3 + 0], w1 = swq[rl * 3 + 1], w2 = swq[rl * 3 + 2];
        const float* g0 = G + (size_t)(bS + siq[rl * 3 + 0]) * COUT;
        const float* g1 = G + (size_t)(bS + siq[rl * 3 + 1]) * COUT;
        const float* g2 = G + (size_t)(bS + siq[rl * 3 + 2]) * COUT;
#pragma unroll
        for (int tn = 0; tn < 4; ++tn) {
          int col = w * 64 + tn * 16 + l16;
          float gv = fmaf(w0, g0[col], fmaf(w1, g1[col], w2 * g2[col]));
          float v = acc[tm][tn][r] + bias[tn] + gv;
          v = v > 0.f ? v : 0.f;
          Hs[rl * 264 + col] = f2bf(v);
        }
      }
  }

  // ---- phase 2: Hs @ W2 + LN, double-buffered B, 1 barrier/iter ----
#pragma unroll
  for (int tm = 0; tm < 4; ++tm)
#pragma unroll
    for (int tn = 0; tn < 4; ++tn) acc[tm][tn] = zero;

  __syncthreads();               // Hs writes visible; phase-1 Bs reads done
#pragma unroll
  for (int r = 0; r < 4; ++r) {  // stage kc=0 into Bs
    int u = tid + r * 256;
    int nrow = u >> 2, c = u & 3;
    int cg = c ^ (nrow & 3);
    gl_lds16(W2T + (size_t)nrow * COUT + cg * 8, (char*)Bs + u * 16);
  }
  for (int kc = 0; kc < 8; ++kc) {
    __syncthreads();             // B(kc) staged (vmcnt drained at barrier)
    u16* cur = (kc & 1) ? Bs2 : Bs;
    u16* nxt = (kc & 1) ? Bs : Bs2;
    if (kc + 1 < 8) {
#pragma unroll
      for (int r = 0; r < 4; ++r) {
        int u = tid + r * 256;
        int nrow = u >> 2, c = u & 3;
        int cg = c ^ (nrow & 3);
        gl_lds16(W2T + (size_t)nrow * COUT + (kc + 1) * 32 + cg * 8,
                 (char*)nxt + u * 16);
      }
    }
    short8 af[4], bf[4];
#pragma unroll
    for (int t = 0; t < 4; ++t)
      af[t] = *(const short8*)(Hs + (t * 16 + l16) * 264 + kc * 32 + quad * 8);
#pragma unroll
    for (int t = 0; t < 4; ++t) {
      int rr = w * 64 + t * 16 + l16;
      bf[t] = *(const short8*)(cur + (rr * 4 + (quad ^ (rr & 3))) * 8);
    }
#pragma unroll
    for (int tm = 0; tm < 4; ++tm)
#pragma unroll
      for (int tn = 0; tn < 4; ++tn)
        acc[tm][tn] = __builtin_amdgcn_mfma_f32_16x16x32_bf16(af[tm], bf[tn], acc[tm][tn], 0, 0, 0);
  }

  float bias[4], g[4], be[4];
#pragma unroll
  for (int tn = 0; tn < 4; ++tn) {
    int col = w * 64 + tn * 16 + l16;
    bias[tn] = b2[col]; g[tn] = gamma[col]; be[tn] = beta[col];
  }
#pragma unroll
  for (int tm = 0; tm < 4; ++tm)
#pragma unroll
    for (int r = 0; r < 4; ++r) {
      float s = 0.f, sq = 0.f;
#pragma unroll
      for (int tn = 0; tn < 4; ++tn) {
        float v = acc[tm][tn][r] + bias[tn];
        acc[tm][tn][r] = v;
        s += v; sq += v * v;
      }
#pragma unroll
      for (int msk = 1; msk < 16; msk <<= 1) {
        s += __shfl_xor(s, msk);
        sq += __shfl_xor(sq, msk);
      }
      if (l16 == 0) {
        int rl = tm * 16 + quad * 4 + r;
        red[w][rl][0] = s;
        red[w][rl][1] = sq;
      }
    }
  __syncthreads();
  if (tid < 64) {
    float s = red[0][tid][0] + red[1][tid][0] + red[2][tid][0] + red[3][tid][0];
    float sq = red[0][tid][1] + red[1][tid][1] + red[2][tid][1] + red[3][tid][1];
    float mu = s * (1.f / 256.f);
    float var = sq * (1.f / 256.f) - mu * mu;
    stats[tid][0] = mu;
    stats[tid][1] = rsqrtf(var + 1e-5f);
  }
  __syncthreads();
#pragma unroll
  for (int tm = 0; tm < 4; ++tm)
#pragma unroll
    for (int r = 0; r < 4; ++r) {
      int rl = tm * 16 + quad * 4 + r;
      float mu = stats[rl][0], rstd = stats[rl][1];
#pragma unroll
      for (int tn = 0; tn < 4; ++tn) {
        int col = w * 64 + tn * 16 + l16;
        out[(size_t)(m0 + rl) * COUT + col] = (acc[tm][tn][r] - mu) * rstd * g[tn] + be[tn];
      }
    }
}

// ---------------------------------------------------------------------------
extern "C" void kernel_launch(void* const* d_in, const int* in_sizes, int n_in,
                              void* d_out, int out_size, void* d_ws, size_t ws_size,
                              hipStream_t stream) {
  const float* xyz_hi    = (const float*)d_in[0];
  const float* xyz_lo    = (const float*)d_in[1];
  const float* feat_skip = (const float*)d_in[2];
  const float* feat_lo   = (const float*)d_in[3];
  const float* W1        = (const float*)d_in[4];
  const float* b1        = (const float*)d_in[5];
  const float* W2        = (const float*)d_in[6];
  const float* b2        = (const float*)d_in[7];
  const float* gamma     = (const float*)d_in[8];
  const float* beta      = (const float*)d_in[9];
  float* out = (float*)d_out;

  char* ws = (char*)d_ws;
  u16*   FSB   = (u16*)(ws + 0);                 // 16777216 (feat_skip bf16)
  u16*   W1aT  = (u16*)(ws + 16777216);          // 131072
  u16*   W1bT  = (u16*)(ws + 16908288);          // 262144
  u16*   W2T   = (u16*)(ws + 17170432);          // 131072
  float* wq_g  = (float*)(ws + 17301504);        // 393216
  int*   iq_g  = (int*)(ws + 17694720);          // 393216
  float* G     = (float*)(ws + 18087936);        // 8388608
  u16*   FLB   = (u16*)(ws + 26476544);          // 8388608 (feat_lo bf16)

  knn_wconv_kernel<<<576, 1024, 0, stream>>>(xyz_hi, xyz_lo, W1, W2,
                                             feat_skip, feat_lo,
                                             wq_g, iq_g, W1aT, W1bT, W2T,
                                             FSB, FLB);
  ggemm_kernel<<<(BB * SS) / 32 * 2, 256, 0, stream>>>(FLB, W1bT, G);
  gemm12_kernel<<<MTOT / 64, 256, 0, stream>>>(FSB, W1aT, b1, G, wq_g, iq_g,
                                               W2T, b2, gamma, beta, out);
}

// Round 10
// 174.133 us; speedup vs baseline: 1.1799x; 1.0010x over previous
//
#include <hip/hip_runtime.h>
#include <hip/hip_bf16.h>
#include <stdint.h>

typedef unsigned short u16;
typedef __attribute__((ext_vector_type(8))) short short8;
typedef __attribute__((ext_vector_type(4))) float f32x4;

#define BB 4
#define NN 8192
#define SS 2048
#define MTOT 32768
#define CSKIP 256
#define CLO 512
#define CIN 768
#define COUT 256

__device__ __forceinline__ u16 f2bf(float f) {
  unsigned u = __float_as_uint(f);
  u += 0x7fffu + ((u >> 16) & 1u);
  return (u16)(u >> 16);
}

__device__ __forceinline__ void gl_lds16(const void* g, void* l) {
  __builtin_amdgcn_global_load_lds(
      (const __attribute__((address_space(1))) void*)g,
      (__attribute__((address_space(3))) void*)l, 16, 0, 0);
}

__device__ __forceinline__ void pack_store(u16* d, float4 x0, float4 x1) {
  union { u16 a[8]; short8 v; } pk;
  pk.a[0] = f2bf(x0.x); pk.a[1] = f2bf(x0.y);
  pk.a[2] = f2bf(x0.z); pk.a[3] = f2bf(x0.w);
  pk.a[4] = f2bf(x1.x); pk.a[5] = f2bf(x1.y);
  pk.a[6] = f2bf(x1.z); pk.a[7] = f2bf(x1.w);
  *(short8*)d = pk.v;
}

// ---------------------------------------------------------------------------
// K1: grid 576. (R9-measured 46 us; unchanged.)
//   blocks 0..511: KNN (R5-exact VALU structure) + feat bf16 conversion
//     overlapped (early-issued float4 loads ride under the VALU-bound knn
//     phase; pack+store tail after the merge).
//   blocks 512..575: weight transposes (W1aT/W1bT/W2T).
// ---------------------------------------------------------------------------
__global__ __launch_bounds__(1024) void knn_wconv_kernel(
    const float* __restrict__ xyz_hi, const float* __restrict__ xyz_lo,
    const float* __restrict__ W1, const float* __restrict__ W2,
    const float* __restrict__ feat_skip, const float* __restrict__ feat_lo,
    float* __restrict__ wq_g, int* __restrict__ iq_g,
    u16* __restrict__ W1aT, u16* __restrict__ W1bT, u16* __restrict__ W2T,
    u16* __restrict__ FSB, u16* __restrict__ FLB) {
  int blk = blockIdx.x;
  int tid = threadIdx.x;

  if (blk >= 512) {
    // ---- wconv: 262144 weight elems over 64 blocks x 1024 thr ----
    int base = (blk - 512) * 1024 + tid;
    for (int i = base; i < 262144; i += 65536) {
      if (i < 65536) {                       // W1aT: n=i>>8, k=i&255
        int n = i >> 8, k = i & 255;
        W1aT[i] = f2bf(W1[(size_t)k * COUT + n]);
      } else if (i < 196608) {               // W1bT: n=j>>9, k=j&511
        int j = i - 65536;
        int n = j >> 9, k = j & 511;
        W1bT[j] = f2bf(W1[(size_t)(256 + k) * COUT + n]);
      } else {                               // W2T
        int j = i - 196608;
        int n = j >> 8, k = j & 255;
        W2T[j] = f2bf(W2[(size_t)k * COUT + n]);
      }
    }
    return;
  }

  // ---- knn block: early-issue conversion loads (overlap knn VALU) ----
  int wtid = blk * 1024 + tid;               // 0..524287
  int t0 = wtid;
  int p0 = t0 & 3, r0 = (t0 >> 2) & 32767, k0 = t0 >> 17;
  const float* s0 = feat_skip + (size_t)r0 * CSKIP + k0 * 32 + (p0 ^ (r0 & 3)) * 8;
  int t1 = wtid + 524288;
  int p1 = t1 & 3, r1 = (t1 >> 2) & 32767, k1 = t1 >> 17;
  const float* s1 = feat_skip + (size_t)r1 * CSKIP + k1 * 32 + (p1 ^ (r1 & 3)) * 8;
  int p2 = wtid & 3, r2 = (wtid >> 2) & 8191, k2 = wtid >> 15;
  const float* s2 = feat_lo + (size_t)r2 * CLO + k2 * 32 + (p2 ^ (r2 & 3)) * 8;
  float4 c0a = *(const float4*)s0, c0b = *(const float4*)(s0 + 4);
  float4 c1a = *(const float4*)s1, c1b = *(const float4*)(s1 + 4);
  float4 c2a = *(const float4*)s2, c2b = *(const float4*)(s2 + 4);

  // ---- knn (R5-exact) ----
  __shared__ float md[16][64][3];
  __shared__ int   mi[16][64][3];

  int b = blk >> 7;
  int wave = tid >> 6, lane = tid & 63;
  int qm = blk * 64 + lane;
  float qx = xyz_hi[(size_t)qm * 3 + 0];
  float qy = xyz_hi[(size_t)qm * 3 + 1];
  float qz = xyz_hi[(size_t)qm * 3 + 2];

  const float* xl = xyz_lo + (size_t)b * SS * 3;
  int j0 = __builtin_amdgcn_readfirstlane(wave * 128);

  float b0 = 1e30f, b1 = 1e30f, b2 = 1e30f;
  int i0 = -1, i1 = -1, i2 = -1;
#pragma unroll 8
  for (int jj = 0; jj < 128; ++jj) {
    int j = j0 + jj;
    float px = xl[3 * j + 0];            // uniform -> scalar load / broadcast
    float py = xl[3 * j + 1];
    float pz = xl[3 * j + 2];
    float dx = px - qx, dy = py - qy, dz = pz - qz;
    float d = fmaf(dx, dx, fmaf(dy, dy, dz * dz));
    bool c0 = d < b0, c1 = d < b1, c2 = d < b2;
    float nb0 = fminf(b0, d);
    float nb1 = __builtin_amdgcn_fmed3f(b0, b1, d);
    float nb2 = __builtin_amdgcn_fmed3f(b1, b2, d);
    int ni0 = c0 ? j : i0;
    int ni1 = c0 ? i0 : (c1 ? j : i1);
    int ni2 = c1 ? i1 : (c2 ? j : i2);
    b0 = nb0; b1 = nb1; b2 = nb2;
    i0 = ni0; i1 = ni1; i2 = ni2;
  }
  md[wave][lane][0] = b0; mi[wave][lane][0] = i0;
  md[wave][lane][1] = b1; mi[wave][lane][1] = i1;
  md[wave][lane][2] = b2; mi[wave][lane][2] = i2;
  __syncthreads();

  if (tid < 64) {
    int q = tid;
    float fb0 = 1e30f, fb1 = 1e30f, fb2 = 1e30f;
    int fi0 = -1, fi1 = -1, fi2 = -1;
    // parts are contiguous ascending ranges; merge with index tiebreak
    for (int p = 0; p < 16; ++p)
#pragma unroll
      for (int s = 0; s < 3; ++s) {
        float d = md[p][q][s]; int ix = mi[p][q][s];
        if (d < fb2 || (d == fb2 && ix < fi2)) {
          fb2 = d; fi2 = ix;
          if (fb2 < fb1 || (fb2 == fb1 && fi2 < fi1)) {
            float t = fb1; fb1 = fb2; fb2 = t; int ti = fi1; fi1 = fi2; fi2 = ti;
          }
          if (fb1 < fb0 || (fb1 == fb0 && fi1 < fi0)) {
            float t = fb0; fb0 = fb1; fb1 = t; int ti = fi0; fi0 = fi1; fi1 = ti;
          }
        }
      }
    int qm2 = blk * 64 + q;
    float d0 = sqrtf(fb0), d1 = sqrtf(fb1), d2 = sqrtf(fb2);
    float inv0 = 1.0f / (d0 + 1e-8f);
    float inv1 = 1.0f / (d1 + 1e-8f);
    float inv2 = 1.0f / (d2 + 1e-8f);
    float s = inv0 + inv1 + inv2;
    wq_g[(size_t)qm2 * 3 + 0] = inv0 / s;
    wq_g[(size_t)qm2 * 3 + 1] = inv1 / s;
    wq_g[(size_t)qm2 * 3 + 2] = inv2 / s;
    iq_g[(size_t)qm2 * 3 + 0] = fi0;
    iq_g[(size_t)qm2 * 3 + 1] = fi1;
    iq_g[(size_t)qm2 * 3 + 2] = fi2;
  }

  // ---- conversion tail: pack + store (data arrived during knn phase) ----
  pack_store(FSB + (size_t)t0 * 8, c0a, c0b);
  pack_store(FSB + (size_t)t1 * 8, c1a, c1b);
  pack_store(FLB + (size_t)wtid * 8, c2a, c2b);
}

// ---------------------------------------------------------------------------
// K2: ggemm — G = feat_lo @ W1b  (dense, M=8192, K=512, N=256, fp32 out).
// Tile 32x128, 256 thr, BK=32, grid 512, dbuf 1 barrier/kc; A staged from
// pre-converted FLB via ONE linear gl_lds16 (tid<128).
// (R8/R9-measured ~10.5 us; unchanged.)
// ---------------------------------------------------------------------------
__global__ __launch_bounds__(256, 4) void ggemm_kernel(
    const u16* __restrict__ FLB, const u16* __restrict__ W1bT,
    float* __restrict__ G) {
  __shared__ u16 As[2][32 * 32];
  __shared__ u16 Bs[2][128 * 32];
  int tid = threadIdx.x;
  int m0 = (blockIdx.x >> 1) << 5;
  int n0 = (blockIdx.x & 1) << 7;
  int w = tid >> 6, lane = tid & 63;
  int quad = lane >> 4, l16 = lane & 15;

  f32x4 zero = {0.f, 0.f, 0.f, 0.f};
  f32x4 acc[2][2];
#pragma unroll
  for (int tm = 0; tm < 2; ++tm)
#pragma unroll
    for (int tn = 0; tn < 2; ++tn) acc[tm][tn] = zero;

  auto stageA = [&](u16* An, int kc) {
    if (tid < 128)
      gl_lds16((const char*)(FLB + ((size_t)kc * NN + m0) * 32) + tid * 16,
               (char*)An + tid * 16);
  };
  auto stageB = [&](u16* Bn, int kc) {
#pragma unroll
    for (int r = 0; r < 2; ++r) {
      int u = tid + r * 256;
      int nrow = u >> 2, c = u & 3;
      int cg = c ^ (nrow & 3);
      gl_lds16(W1bT + (size_t)(n0 + nrow) * CLO + kc * 32 + cg * 8,
               (char*)Bn + u * 16);
    }
  };

  stageB(Bs[0], 0);
  stageA(As[0], 0);

  for (int kc = 0; kc < 16; ++kc) {
    __syncthreads();             // buf[cur] staged+visible; buf[nxt] reads done
    const u16* Ac = As[kc & 1];
    const u16* Bc = Bs[kc & 1];
    if (kc + 1 < 16) {
      stageB(Bs[(kc + 1) & 1], kc + 1);
      stageA(As[(kc + 1) & 1], kc + 1);
    }

    short8 af[2], bf[2];
#pragma unroll
    for (int t = 0; t < 2; ++t) {
      int rr = t * 16 + l16;
      af[t] = *(const short8*)(Ac + (rr * 4 + (quad ^ (rr & 3))) * 8);
    }
#pragma unroll
    for (int t = 0; t < 2; ++t) {
      int rr = w * 32 + t * 16 + l16;
      bf[t] = *(const short8*)(Bc + (rr * 4 + (quad ^ (rr & 3))) * 8);
    }
#pragma unroll
    for (int tm = 0; tm < 2; ++tm)
#pragma unroll
      for (int tn = 0; tn < 2; ++tn)
        acc[tm][tn] = __builtin_amdgcn_mfma_f32_16x16x32_bf16(af[tm], bf[tn], acc[tm][tn], 0, 0, 0);
  }

#pragma unroll
  for (int tm = 0; tm < 2; ++tm)
#pragma unroll
    for (int tn = 0; tn < 2; ++tn) {
      int col = n0 + w * 32 + tn * 16 + l16;
#pragma unroll
      for (int r = 0; r < 4; ++r) {
        int row = m0 + tm * 16 + quad * 4 + r;
        G[(size_t)row * COUT + col] = acc[tm][tn][r];
      }
    }
}

// ---------------------------------------------------------------------------
// K3: fused MLP — phase 1: Htile = relu(skip@W1a + b1 + IDW-gather(G)) -> LDS
// (bf16, rows padded to 264); phase 2: out = LN(Htile@W2 + b2).
// R10: T14 async-split on the IDW gather — the tm=0 chunk's 48 G-loads are
// issued at kc=6 and tm=1's at kc=7 into statically-indexed register arrays
// (96 VGPR; peak ~180 incl. acc — LDS caps occupancy at 2 blocks/CU so the
// VGPRs are free). Their latency hides under kc6/kc7 MFMA + epilogue
// compute instead of being a serial tail. tm=2/3 stay on the pointer path
// (overlap tm=0/1 compute). R1's spill lesson: static indices, bounded
// register count, no per-kc vmcnt coupling.
// ---------------------------------------------------------------------------
__global__ __launch_bounds__(256, 2) void gemm12_kernel(
    const u16* __restrict__ FSB, const u16* __restrict__ W1aT,
    const float* __restrict__ b1, const float* __restrict__ G,
    const float* __restrict__ wq_g, const int* __restrict__ iq_g,
    const u16* __restrict__ W2T, const float* __restrict__ b2,
    const float* __restrict__ gamma, const float* __restrict__ beta,
    float* __restrict__ out) {
  __shared__ u16 Hs[64 * 264];
  __shared__ u16 Bs[256 * 32];
  __shared__ u16 Bs2[256 * 32];
  __shared__ u16 As[2][64 * 32];
  __shared__ float swq[192];
  __shared__ int   siq[192];
  __shared__ float red[4][64][2];
  __shared__ float stats[64][2];
  int tid = threadIdx.x;
  int m0 = blockIdx.x << 6;
  int bS = (m0 >> 13) * SS;
  int w = tid >> 6, lane = tid & 63;
  int quad = lane >> 4, l16 = lane & 15;

  if (tid < 192) {
    swq[tid] = wq_g[(size_t)m0 * 3 + tid];
    siq[tid] = iq_g[(size_t)m0 * 3 + tid];
  }

  f32x4 zero = {0.f, 0.f, 0.f, 0.f};
  f32x4 acc[4][4];
#pragma unroll
  for (int tm = 0; tm < 4; ++tm)
#pragma unroll
    for (int tn = 0; tn < 4; ++tn) acc[tm][tn] = zero;

  auto stageA = [&](u16* An, int kc) {
    gl_lds16((const char*)(FSB + ((size_t)kc * MTOT + m0) * 32) + tid * 16,
             (char*)An + tid * 16);
  };

  // prefetched gather values for tm=0 (issued kc=6) and tm=1 (issued kc=7)
  float ga0[16], gb0[16], gc0[16];
  float ga1[16], gb1[16], gc1[16];

  // ---- phase 1 prologue: stage kc=0 (Bs <- W1aT, As[0] <- FSB) ----
#pragma unroll
  for (int r = 0; r < 4; ++r) {
    int u = tid + r * 256;
    int nrow = u >> 2, c = u & 3;
    int cg = c ^ (nrow & 3);
    gl_lds16(W1aT + (size_t)nrow * CSKIP + cg * 8, (char*)Bs + u * 16);
  }
  stageA(As[0], 0);

  // ---- phase 1: skip @ W1a — double-buffered, 1 barrier/kc ----
  for (int kc = 0; kc < 8; ++kc) {
    __syncthreads();             // buf[cur] staged+visible; buf[nxt] reads done
    const u16* Ac = As[kc & 1];
    u16* Bc = (kc & 1) ? Bs2 : Bs;
    if (kc + 1 < 8) {
      u16* Bn = (kc & 1) ? Bs : Bs2;
#pragma unroll
      for (int r = 0; r < 4; ++r) {
        int u = tid + r * 256;
        int nrow = u >> 2, c = u & 3;
        int cg = c ^ (nrow & 3);
        gl_lds16(W1aT + (size_t)nrow * CSKIP + (kc + 1) * 32 + cg * 8,
                 (char*)Bn + u * 16);
      }
      stageA(As[(kc + 1) & 1], kc + 1);
    }

    if (kc == 6) {               // issue tm=0 gather (uses swq/siq: synced)
#pragma unroll
      for (int r = 0; r < 4; ++r) {
        int rl = quad * 4 + r;
        const float* g0 = G + (size_t)(bS + siq[rl * 3 + 0]) * COUT;
        const float* g1 = G + (size_t)(bS + siq[rl * 3 + 1]) * COUT;
        const float* g2 = G + (size_t)(bS + siq[rl * 3 + 2]) * COUT;
#pragma unroll
        for (int tn = 0; tn < 4; ++tn) {
          int col = w * 64 + tn * 16 + l16;
          ga0[r * 4 + tn] = g0[col];
          gb0[r * 4 + tn] = g1[col];
          gc0[r * 4 + tn] = g2[col];
        }
      }
    }
    if (kc == 7) {               // issue tm=1 gather
#pragma unroll
      for (int r = 0; r < 4; ++r) {
        int rl = 16 + quad * 4 + r;
        const float* g0 = G + (size_t)(bS + siq[rl * 3 + 0]) * COUT;
        const float* g1 = G + (size_t)(bS + siq[rl * 3 + 1]) * COUT;
        const float* g2 = G + (size_t)(bS + siq[rl * 3 + 2]) * COUT;
#pragma unroll
        for (int tn = 0; tn < 4; ++tn) {
          int col = w * 64 + tn * 16 + l16;
          ga1[r * 4 + tn] = g0[col];
          gb1[r * 4 + tn] = g1[col];
          gc1[r * 4 + tn] = g2[col];
        }
      }
    }

    short8 af[4], bf[4];
#pragma unroll
    for (int t = 0; t < 4; ++t) {
      int rr = t * 16 + l16;
      af[t] = *(const short8*)(Ac + (rr * 4 + (quad ^ (rr & 3))) * 8);
    }
#pragma unroll
    for (int t = 0; t < 4; ++t) {
      int rr = w * 64 + t * 16 + l16;
      bf[t] = *(const short8*)(Bc + (rr * 4 + (quad ^ (rr & 3))) * 8);
    }
#pragma unroll
    for (int tm = 0; tm < 4; ++tm)
#pragma unroll
      for (int tn = 0; tn < 4; ++tn)
        acc[tm][tn] = __builtin_amdgcn_mfma_f32_16x16x32_bf16(af[tm], bf[tn], acc[tm][tn], 0, 0, 0);
  }

  // ---- phase 1 epilogue: bias + IDW (tm0/1 prefetched) + relu -> Hs ----
  {
    float bias[4];
#pragma unroll
    for (int tn = 0; tn < 4; ++tn) bias[tn] = b1[w * 64 + tn * 16 + l16];
    // tm = 0: prefetched
#pragma unroll
    for (int r = 0; r < 4; ++r) {
      int rl = quad * 4 + r;
      float w0 = swq[rl * 3 + 0], w1 = swq[rl * 3 + 1], w2 = swq[rl * 3 + 2];
#pragma unroll
      for (int tn = 0; tn < 4; ++tn) {
        int col = w * 64 + tn * 16 + l16;
        float gv = fmaf(w0, ga0[r * 4 + tn],
                        fmaf(w1, gb0[r * 4 + tn], w2 * gc0[r * 4 + tn]));
        float v = acc[0][tn][r] + bias[tn] + gv;
        v = v > 0.f ? v : 0.f;
        Hs[rl * 264 + col] = f2bf(v);
      }
    }
    // tm = 1: prefetched
#pragma unroll
    for (int r = 0; r < 4; ++r) {
      int rl = 16 + quad * 4 + r;
      float w0 = swq[rl * 3 + 0], w1 = swq[rl * 3 + 1], w2 = swq[rl * 3 + 2];
#pragma unroll
      for (int tn = 0; tn < 4; ++tn) {
        int col = w * 64 + tn * 16 + l16;
        float gv = fmaf(w0, ga1[r * 4 + tn],
                        fmaf(w1, gb1[r * 4 + tn], w2 * gc1[r * 4 + tn]));
        float v = acc[1][tn][r] + bias[tn] + gv;
        v = v > 0.f ? v : 0.f;
        Hs[rl * 264 + col] = f2bf(v);
      }
    }
    // tm = 2,3: pointer path (loads overlap tm0/1 compute above)
#pragma unroll
    for (int tm = 2; tm < 4; ++tm)
#pragma unroll
      for (int r = 0; r < 4; ++r) {
        int rl = tm * 16 + quad * 4 + r;
        float w0 = swq[rl * 3 + 0], w1 = swq[rl * 3 + 1], w2 = swq[rl * 3 + 2];
        const float* g0 = G + (size_t)(bS + siq[rl * 3 + 0]) * COUT;
        const float* g1 = G + (size_t)(bS + siq[rl * 3 + 1]) * COUT;
        const float* g2 = G + (size_t)(bS + siq[rl * 3 + 2]) * COUT;
#pragma unroll
        for (int tn = 0; tn < 4; ++tn) {
          int col = w * 64 + tn * 16 + l16;
          float gv = fmaf(w0, g0[col], fmaf(w1, g1[col], w2 * g2[col]));
          float v = acc[tm][tn][r] + bias[tn] + gv;
          v = v > 0.f ? v : 0.f;
          Hs[rl * 264 + col] = f2bf(v);
        }
      }
  }

  // ---- phase 2: Hs @ W2 + LN, double-buffered B, 1 barrier/iter ----
#pragma unroll
  for (int tm = 0; tm < 4; ++tm)
#pragma unroll
    for (int tn = 0; tn < 4; ++tn) acc[tm][tn] = zero;

  __syncthreads();               // Hs writes visible; phase-1 Bs reads done
#pragma unroll
  for (int r = 0; r < 4; ++r) {  // stage kc=0 into Bs
    int u = tid + r * 256;
    int nrow = u >> 2, c = u & 3;
    int cg = c ^ (nrow & 3);
    gl_lds16(W2T + (size_t)nrow * COUT + cg * 8, (char*)Bs + u * 16);
  }
  for (int kc = 0; kc < 8; ++kc) {
    __syncthreads();             // B(kc) staged (vmcnt drained at barrier)
    u16* cur = (kc & 1) ? Bs2 : Bs;
    u16* nxt = (kc & 1) ? Bs : Bs2;
    if (kc + 1 < 8) {
#pragma unroll
      for (int r = 0; r < 4; ++r) {
        int u = tid + r * 256;
        int nrow = u >> 2, c = u & 3;
        int cg = c ^ (nrow & 3);
        gl_lds16(W2T + (size_t)nrow * COUT + (kc + 1) * 32 + cg * 8,
                 (char*)nxt + u * 16);
      }
    }
    short8 af[4], bf[4];
#pragma unroll
    for (int t = 0; t < 4; ++t)
      af[t] = *(const short8*)(Hs + (t * 16 + l16) * 264 + kc * 32 + quad * 8);
#pragma unroll
    for (int t = 0; t < 4; ++t) {
      int rr = w * 64 + t * 16 + l16;
      bf[t] = *(const short8*)(cur + (rr * 4 + (quad ^ (rr & 3))) * 8);
    }
#pragma unroll
    for (int tm = 0; tm < 4; ++tm)
#pragma unroll
      for (int tn = 0; tn < 4; ++tn)
        acc[tm][tn] = __builtin_amdgcn_mfma_f32_16x16x32_bf16(af[tm], bf[tn], acc[tm][tn], 0, 0, 0);
  }

  float bias[4], g[4], be[4];
#pragma unroll
  for (int tn = 0; tn < 4; ++tn) {
    int col = w * 64 + tn * 16 + l16;
    bias[tn] = b2[col]; g[tn] = gamma[col]; be[tn] = beta[col];
  }
#pragma unroll
  for (int tm = 0; tm < 4; ++tm)
#pragma unroll
    for (int r = 0; r < 4; ++r) {
      float s = 0.f, sq = 0.f;
#pragma unroll
      for (int tn = 0; tn < 4; ++tn) {
        float v = acc[tm][tn][r] + bias[tn];
        acc[tm][tn][r] = v;
        s += v; sq += v * v;
      }
#pragma unroll
      for (int msk = 1; msk < 16; msk <<= 1) {
        s += __shfl_xor(s, msk);
        sq += __shfl_xor(sq, msk);
      }
      if (l16 == 0) {
        int rl = tm * 16 + quad * 4 + r;
        red[w][rl][0] = s;
        red[w][rl][1] = sq;
      }
    }
  __syncthreads();
  if (tid < 64) {
    float s = red[0][tid][0] + red[1][tid][0] + red[2][tid][0] + red[3][tid][0];
    float sq = red[0][tid][1] + red[1][tid][1] + red[2][tid][1] + red[3][tid][1];
    float mu = s * (1.f / 256.f);
    float var = sq * (1.f / 256.f) - mu * mu;
    stats[tid][0] = mu;
    stats[tid][1] = rsqrtf(var + 1e-5f);
  }
  __syncthreads();
#pragma unroll
  for (int tm = 0; tm < 4; ++tm)
#pragma unroll
    for (int r = 0; r < 4; ++r) {
      int rl = tm * 16 + quad * 4 + r;
      float mu = stats[rl][0], rstd = stats[rl][1];
#pragma unroll
      for (int tn = 0; tn < 4; ++tn) {
        int col = w * 64 + tn * 16 + l16;
        out[(size_t)(m0 + rl) * COUT + col] = (acc[tm][tn][r] - mu) * rstd * g[tn] + be[tn];
      }
    }
}

// ---------------------------------------------------------------------------
extern "C" void kernel_launch(void* const* d_in, const int* in_sizes, int n_in,
                              void* d_out, int out_size, void* d_ws, size_t ws_size,
                              hipStream_t stream) {
  const float* xyz_hi    = (const float*)d_in[0];
  const float* xyz_lo    = (const float*)d_in[1];
  const float* feat_skip = (const float*)d_in[2];
  const float* feat_lo   = (const float*)d_in[3];
  const float* W1        = (const float*)d_in[4];
  const float* b1        = (const float*)d_in[5];
  const float* W2        = (const float*)d_in[6];
  const float* b2        = (const float*)d_in[7];
  const float* gamma     = (const float*)d_in[8];
  const float* beta      = (const float*)d_in[9];
  float* out = (float*)d_out;

  char* ws = (char*)d_ws;
  u16*   FSB   = (u16*)(ws + 0);                 // 16777216 (feat_skip bf16)
  u16*   W1aT  = (u16*)(ws + 16777216);          // 131072
  u16*   W1bT  = (u16*)(ws + 16908288);          // 262144
  u16*   W2T   = (u16*)(ws + 17170432);          // 131072
  float* wq_g  = (float*)(ws + 17301504);        // 393216
  int*   iq_g  = (int*)(ws + 17694720);          // 393216
  float* G     = (float*)(ws + 18087936);        // 8388608
  u16*   FLB   = (u16*)(ws + 26476544);          // 8388608 (feat_lo bf16)

  knn_wconv_kernel<<<576, 1024, 0, stream>>>(xyz_hi, xyz_lo, W1, W2,
                                             feat_skip, feat_lo,
                                             wq_g, iq_g, W1aT, W1bT, W2T,
                                             FSB, FLB);
  ggemm_kernel<<<(BB * SS) / 32 * 2, 256, 0, stream>>>(FLB, W1bT, G);
  gemm12_kernel<<<MTOT / 64, 256, 0, stream>>>(FSB, W1aT, b1, G, wq_g, iq_g,
                                               W2T, b2, gamma, beta, out);
}